// Round 1
// 121.285 us; speedup vs baseline: 1.0325x; 1.0325x over previous
//
#include <hip/hip_runtime.h>
#include <math.h>

// Problem constants
constexpr int kB  = 8;
constexpr int kNL = 48;
constexpr int kNT = 512;
constexpr int kH  = 128;
constexpr int kG  = 10;

constexpr int kRowsL = kB * kNL;          // 384
constexpr int kRowsT = kB * kNT;          // 4096
constexpr int kRows  = kRowsL + kRowsT;   // 4480
constexpr int kM     = kB * kNL * kNT;    // 196608
constexpr float kEps = 1e-5f;

// Output layout (flat concat, reference return order)
constexpr size_t OFF_PI = 0;
constexpr size_t OFF_SG = (size_t)kM * kG;
constexpr size_t OFF_MU = 2 * (size_t)kM * kG;
constexpr size_t OFF_D  = 3 * (size_t)kM * kG;
constexpr size_t OFF_CB = OFF_D + kM;

typedef __attribute__((ext_vector_type(8))) short short8;   // 8 bf16 (4 VGPR)
typedef __attribute__((ext_vector_type(4))) float f32x4;    // MFMA C/D

__device__ __forceinline__ short f2bf(float f) {            // RNE float->bf16
    unsigned u = __builtin_bit_cast(unsigned, f);
    unsigned r = u + 0x7fffu + ((u >> 16) & 1u);
    return (short)(r >> 16);
}
__device__ __forceinline__ float elu_f(float x) {
    return x > 0.0f ? x : (__expf(x) - 1.0f);
}

// ---------------------------------------------------------------------------
// prep_sp: [4480x128] @ (BN-scaled W1)^T via bf16 MFMA, self-packing W1
// fragments per block. Block 280 packs the MERGED projection-weight image:
// the 30 useful output columns (pi:10, sg:10, mu:10) are packed into TWO
// MFMA n-tiles instead of three:
//   ntile0: col n<10 -> pi[n],     col 10..15 -> sg[n-10]
//   ntile1: col n<4  -> sg[n+6],   col 4..13  -> mu[n-4],  col 14,15 -> 0
// This cuts the pair kernel from 24 to 16 MFMAs/wave and 48->32 B-frag VGPRs.
// ---------------------------------------------------------------------------
__global__ __launch_bounds__(256) void prep_sp(
    const float* __restrict__ lig_s, const float* __restrict__ pro_s,
    const float* __restrict__ W1, const float* __restrict__ b1,
    const float* __restrict__ gamma, const float* __restrict__ beta,
    const float* __restrict__ mean, const float* __restrict__ var,
    const float* __restrict__ Wpi, const float* __restrict__ Wsg,
    const float* __restrict__ Wmu,
    float* __restrict__ Al, float* __restrict__ At, short* __restrict__ Wcp)
{
    const int mtile = blockIdx.x;                 // 0..280
    const int tid = threadIdx.x;

    if (mtile == kRows / 16) {
        // ---- Wcp packer: 4 ktiles x 2 merged ntiles x 64 lanes ----
        for (int idx = tid; idx < 4 * 2 * 64; idx += 256) {
            const int kt = idx / 128, rem = idx % 128, nt = rem >> 6, lane = rem & 63;
            const int n  = lane & 15;
            const int k0 = kt * 32 + (lane >> 4) * 8;
            const float* W = nullptr; int g = 0;
            if (nt == 0) {
                if (n < 10) { W = Wpi; g = n; }
                else        { W = Wsg; g = n - 10; }
            } else {
                if (n < 4)       { W = Wsg; g = n + 6; }
                else if (n < 14) { W = Wmu; g = n - 4; }
            }
            short8 v;
            if (W) {
                const float* wr = W + (size_t)g * kH + k0;
#pragma unroll
                for (int j = 0; j < 8; ++j) v[j] = f2bf(wr[j]);
            } else {
#pragma unroll
                for (int j = 0; j < 8; ++j) v[j] = 0;
            }
            *((short8*)Wcp + idx) = v;
        }
        return;
    }

    const int wave = tid >> 6, lane = tid & 63;
    const int q = lane >> 4, n16 = lane & 15;
    const bool lig = (mtile < kRowsL / 16);       // uniform per block (384=24*16)

    // Self-pack B-fragments: B[k][c] = W1[c][k] * s[c]
    short8 bfrag[2][4];
    float bi[2];
#pragma unroll
    for (int h = 0; h < 2; ++h) {
        const int c = (2 * wave + h) * 16 + n16;
        const float sc = gamma[c] * rsqrtf(var[c] + kEps);
        bi[h] = lig ? ((b1[c] - mean[c]) * sc + beta[c]) : 0.0f;
        const float* wr = W1 + (size_t)c * kH;
#pragma unroll
        for (int kt = 0; kt < 4; ++kt) {
            const float4* w4 = (const float4*)(wr + kt * 32 + q * 8);
            float4 w0 = w4[0], w1 = w4[1];
            short8 v;
            v[0] = f2bf(w0.x * sc); v[1] = f2bf(w0.y * sc);
            v[2] = f2bf(w0.z * sc); v[3] = f2bf(w0.w * sc);
            v[4] = f2bf(w1.x * sc); v[5] = f2bf(w1.y * sc);
            v[6] = f2bf(w1.z * sc); v[7] = f2bf(w1.w * sc);
            bfrag[h][kt] = v;
        }
    }

    const int row = mtile * 16 + n16;
    const float* X = lig ? (lig_s + (size_t)row * kH)
                         : (pro_s + (size_t)(row - kRowsL) * kH);

    f32x4 acc[2] = {};
#pragma unroll
    for (int kt = 0; kt < 4; ++kt) {
        const float4* xp = (const float4*)(X + kt * 32 + q * 8);
        float4 x0 = xp[0], x1 = xp[1];
        short8 a;
        a[0] = f2bf(x0.x); a[1] = f2bf(x0.y); a[2] = f2bf(x0.z); a[3] = f2bf(x0.w);
        a[4] = f2bf(x1.x); a[5] = f2bf(x1.y); a[6] = f2bf(x1.z); a[7] = f2bf(x1.w);
        acc[0] = __builtin_amdgcn_mfma_f32_16x16x32_bf16(a, bfrag[0][kt], acc[0], 0, 0, 0);
        acc[1] = __builtin_amdgcn_mfma_f32_16x16x32_bf16(a, bfrag[1][kt], acc[1], 0, 0, 0);
    }

#pragma unroll
    for (int h = 0; h < 2; ++h) {
        const int c = (2 * wave + h) * 16 + n16;
#pragma unroll
        for (int r = 0; r < 4; ++r) {
            const int R = mtile * 16 + q * 4 + r;
            const float v = acc[h][r] + bi[h];
            if (lig) Al[(size_t)R * kH + c] = v;
            else     At[(size_t)(R - kRowsL) * kH + c] = v;
        }
    }
}

// ---------------------------------------------------------------------------
// pair: per wave, 32 consecutive pairs (2 mtiles) sharing one ligand row.
//   A-frag = bf16(elu(Al[bl]+At[pr])); ligand row hoisted to registers once
//   (loop-invariant -> halves inner-loop global loads). Projection weights
//   resident as 2 merged B-frag n-tiles (32 VGPR) from the pre-packed Wcp.
//   Epilogue: softmax over pi lanes (n<10) of ntile0; sg split across both
//   tiles; mu from ntile1; dist + batch id fused on lanes 0..31.
// Grid: 384*4 blocks x 256 thr; block = (bl, 128-t chunk); wave = 32 t's.
// ---------------------------------------------------------------------------
__global__ __launch_bounds__(256) void pair_mfma(
    const float* __restrict__ Al, const float* __restrict__ At,
    const short* __restrict__ Wcp,
    const float* __restrict__ bpi, const float* __restrict__ bsg,
    const float* __restrict__ bmu,
    const float* __restrict__ lig_pos, const float* __restrict__ pro_pos,
    float* __restrict__ out)
{
    const int blk = blockIdx.x;
    const int bl = blk >> 2, tch = blk & 3;
    const int wave = threadIdx.x >> 6, lane = threadIdx.x & 63;
    const int q = lane >> 4, n = lane & 15;
    const int b = bl / kNL;
    const int t0 = tch * 128 + wave * 32;

    // merged B-fragments (2 ntiles x 4 ktiles), coalesced from packed image
    short8 bf[2][4];
    const short8* wp = (const short8*)Wcp;
#pragma unroll
    for (int kt = 0; kt < 4; ++kt)
#pragma unroll
        for (int ntl = 0; ntl < 2; ++ntl)
            bf[ntl][kt] = wp[(kt * 2 + ntl) * 64 + lane];

    // per-lane bias for the merged column layout
    const float bias0 = (n < 10) ? bpi[n] : bsg[n - 10];
    const float bias1 = (n < 4) ? bsg[n + 6] : ((n < 14) ? bmu[n - 4] : 0.0f);

    // hoist ligand row (loop-invariant across mt/kt): 8 float4 = 32 VGPR
    const float* alp = Al + (size_t)bl * kH;
    float4 al0[4], al1[4];
#pragma unroll
    for (int kt = 0; kt < 4; ++kt) {
        const float4* ap4 = (const float4*)(alp + kt * 32 + q * 8);
        al0[kt] = ap4[0]; al1[kt] = ap4[1];
    }

    f32x4 acc[2][2] = {};
#pragma unroll
    for (int mt = 0; mt < 2; ++mt) {
        const int t = t0 + mt * 16 + n;
        const float* atp = At + (size_t)(b * kNT + t) * kH;
#pragma unroll
        for (int kt = 0; kt < 4; ++kt) {
            const float4* tp4 = (const float4*)(atp + kt * 32 + q * 8);
            float4 t0v = tp4[0], t1v = tp4[1];
            float4 a0 = al0[kt], a1 = al1[kt];
            short8 a;
            a[0] = f2bf(elu_f(a0.x + t0v.x)); a[1] = f2bf(elu_f(a0.y + t0v.y));
            a[2] = f2bf(elu_f(a0.z + t0v.z)); a[3] = f2bf(elu_f(a0.w + t0v.w));
            a[4] = f2bf(elu_f(a1.x + t1v.x)); a[5] = f2bf(elu_f(a1.y + t1v.y));
            a[6] = f2bf(elu_f(a1.z + t1v.z)); a[7] = f2bf(elu_f(a1.w + t1v.w));
            acc[mt][0] = __builtin_amdgcn_mfma_f32_16x16x32_bf16(a, bf[0][kt], acc[mt][0], 0, 0, 0);
            acc[mt][1] = __builtin_amdgcn_mfma_f32_16x16x32_bf16(a, bf[1][kt], acc[mt][1], 0, 0, 0);
        }
    }

    const int pairbase = bl * kNT + t0;
#pragma unroll
    for (int mt = 0; mt < 2; ++mt) {
#pragma unroll
        for (int r = 0; r < 4; ++r) {
            const int m = pairbase + mt * 16 + q * 4 + r;
            const float v0 = acc[mt][0][r] + bias0;  // n<10: pi logit; else sg[n-10]
            const float v1 = acc[mt][1][r] + bias1;  // n<4: sg[n+6]; 4<=n<14: mu[n-4]
            // pi: masked softmax across the 16-lane n-group (pi lanes n<10)
            float mx = (n < 10) ? v0 : -3.0e38f;
#pragma unroll
            for (int d = 1; d < 16; d <<= 1) mx = fmaxf(mx, __shfl_xor(mx, d));
            const float e = (n < 10) ? __expf(v0 - mx) : 0.0f;
            float sm = e;
#pragma unroll
            for (int d = 1; d < 16; d <<= 1) sm += __shfl_xor(sm, d);
            if (n < 10) out[OFF_PI + (size_t)m * kG + n] = e / sm;
            else        out[OFF_SG + (size_t)m * kG + (n - 10)] = elu_f(v0) + 1.1f;
            if (n < 4)       out[OFF_SG + (size_t)m * kG + (n + 6)] = elu_f(v1) + 1.1f;
            else if (n < 14) out[OFF_MU + (size_t)m * kG + (n - 4)] = elu_f(v1) + 1.0f;
        }
    }

    // dist + batch id (lanes 0..31 cover the wave's 32 t's)
    if (lane < 32) {
        const int t = t0 + lane;
        const int pr = b * kNT + t;
        const int m = bl * kNT + t;
        const float dx = lig_pos[(size_t)bl * 3 + 0] - pro_pos[(size_t)pr * 3 + 0];
        const float dy = lig_pos[(size_t)bl * 3 + 1] - pro_pos[(size_t)pr * 3 + 1];
        const float dz = lig_pos[(size_t)bl * 3 + 2] - pro_pos[(size_t)pr * 3 + 2];
        out[OFF_D + m] = sqrtf(dx * dx + dy * dy + dz * dz);
        out[OFF_CB + m] = (float)b;
    }
}

extern "C" void kernel_launch(void* const* d_in, const int* in_sizes, int n_in,
                              void* d_out, int out_size, void* d_ws, size_t ws_size,
                              hipStream_t stream) {
    (void)in_sizes; (void)n_in; (void)out_size; (void)ws_size;
    const float* lig_s    = (const float*)d_in[0];
    const float* lig_pos  = (const float*)d_in[1];
    const float* pro_s    = (const float*)d_in[3];
    const float* pro_pos  = (const float*)d_in[4];
    const float* W1       = (const float*)d_in[6];
    const float* b1       = (const float*)d_in[7];
    const float* bn_gamma = (const float*)d_in[8];
    const float* bn_beta  = (const float*)d_in[9];
    const float* bn_mean  = (const float*)d_in[10];
    const float* bn_var   = (const float*)d_in[11];
    const float* W_pi     = (const float*)d_in[12];
    const float* b_pi     = (const float*)d_in[13];
    const float* W_sigma  = (const float*)d_in[14];
    const float* b_sigma  = (const float*)d_in[15];
    const float* W_mu     = (const float*)d_in[16];
    const float* b_mu     = (const float*)d_in[17];

    float* out = (float*)d_out;
    float* Al  = (float*)d_ws;                               // 384*128 f32
    float* At  = Al + (size_t)kRowsL * kH;                   // 4096*128 f32
    short* Wcp = (short*)(At + (size_t)kRowsT * kH);         // 4*2*64*8 bf16

    prep_sp<<<kRows / 16 + 1, 256, 0, stream>>>(
        lig_s, pro_s, W1, b1, bn_gamma, bn_beta, bn_mean, bn_var,
        W_pi, W_sigma, W_mu, Al, At, Wcp);
    pair_mfma<<<kRowsL * 4, 256, 0, stream>>>(Al, At, Wcp, b_pi, b_sigma, b_mu,
                                              lig_pos, pro_pos, out);
}